// Round 8
// baseline (331.924 us; speedup 1.0000x reference)
//
#include <hip/hip_runtime.h>
#include <cmath>

// Problem constants
#define BB 64
#define TT 128
#define SS 512
#define EE 1024
#define DDIM 512
#define NEG_INF_F (-1.0e10f)

// MFMA tiling
#define BM 128
#define BM2 64   // half-height block (wave tile 32x32)
#define BN 64
#define BK 32
#define LDSTP 20   // padded layout row stride (dwords)
#define ROWU 32    // swizzled plane layout row stride in u16 (64 B/row)

typedef unsigned short u16;
typedef __attribute__((ext_vector_type(8))) short bf16x8;
typedef __attribute__((ext_vector_type(4))) float f32x4;

// Counted-vmcnt pipelining primitives (T4): raw barrier, hand-placed waits.
// __syncthreads() would force vmcnt(0) — that drain is the ~40% stall.
#define SBAR()                                  \
    do {                                        \
        __builtin_amdgcn_sched_barrier(0);      \
        __builtin_amdgcn_s_barrier();           \
        __builtin_amdgcn_sched_barrier(0);      \
    } while (0)
#define WAITVM(N)                                                   \
    do {                                                            \
        asm volatile("s_waitcnt vmcnt(" #N ")" ::: "memory");       \
        __builtin_amdgcn_sched_barrier(0);                          \
    } while (0)
#define WAITLGKM()                                                  \
    do {                                                            \
        asm volatile("s_waitcnt lgkmcnt(0)" ::: "memory");          \
        __builtin_amdgcn_sched_barrier(0);                          \
    } while (0)

// ---------------------------------------------------------------------------
__device__ __forceinline__ unsigned bf16_rne(float f) {
    unsigned u = __float_as_uint(f);
    return (u + 0x7fffu + ((u >> 16) & 1u)) >> 16;
}

// Overflow-safe fast tanh
__device__ __forceinline__ float fast_tanh(float x) {
    float t = __expf(-2.0f * fabsf(x));
    float r = __fdividef(1.0f - t, 1.0f + t);
    return copysignf(r, x);
}

// ---------------------------------------------------------------------------
// glds staging of a bf16 plane tile: ROWS rows x 32 bf16, quad-swizzled.
// Per wave: ROWS/64 vmem instructions (needed for vmcnt bookkeeping).
// ---------------------------------------------------------------------------
template <int ROWS>
__device__ __forceinline__ void stage_glds(u16* lds, const u16* __restrict__ src,
                                           int ld, int tid) {
    const int w = tid >> 6, lane = tid & 63;
    const int rl = lane >> 2, p = lane & 3;
#pragma unroll
    for (int i = 0; i < ROWS / 64; ++i) {
        const int r0 = (w + 4 * i) * 16;
        const int r = r0 + rl;
        const int q = p ^ ((r >> 1) & 3);
        const u16* g = src + (size_t)r * ld + 8 * q;
        __builtin_amdgcn_global_load_lds(
            (const __attribute__((address_space(1))) unsigned*)g,
            (__attribute__((address_space(3))) unsigned*)(lds + r0 * ROWU),
            16, 0, 0);
    }
}

__device__ __forceinline__ bf16x8 read_frag_sw(const u16* buf, int row, int q) {
    const int c = q ^ ((row >> 1) & 3);
    return *(const bf16x8*)(buf + row * ROWU + 8 * c);
}

// ---------------------------------------------------------------------------
// T14 split staging of NT fp32 operand (64 rows x 32 k): load->regs (2 float4/
// thread), pack->padded LDS later (hidden under MFMA).
// ---------------------------------------------------------------------------
__device__ __forceinline__ void nt_load(float4* v, const float* __restrict__ src,
                                        int ld, int tid) {
#pragma unroll
    for (int i = 0; i < 2; ++i) {
        int s = tid + 256 * i;
        int r = s >> 3, kq = s & 7;
        v[i] = *(const float4*)(src + (size_t)r * ld + 4 * kq);
    }
}
__device__ __forceinline__ void nt_pack(unsigned* hi, const float4* v, int tid) {
#pragma unroll
    for (int i = 0; i < 2; ++i) {
        int s = tid + 256 * i;
        int r = s >> 3, kq = s & 7;
        *(uint2*)&hi[r * LDSTP + 2 * kq] =
            make_uint2(bf16_rne(v[i].x) | (bf16_rne(v[i].y) << 16),
                       bf16_rne(v[i].z) | (bf16_rne(v[i].w) << 16));
    }
}

// T14 split staging of transposed fp32 B tile (k_ctx): [32 k][64 n] -> rows=n
__device__ __forceinline__ void tr_load(float4* v, const float* __restrict__ src,
                                        int ld, int tid) {
    int eq = tid & 15;   // n quad
    int sp = tid >> 4;   // k pair
    const float* p = src + (size_t)(2 * sp) * ld + 4 * eq;
    v[0] = *(const float4*)p;
    v[1] = *(const float4*)(p + ld);
}
__device__ __forceinline__ void tr_pack(unsigned* hi, const float4* v, int tid) {
    int eq = tid & 15;
    int sp = tid >> 4;
    float av[4] = {v[0].x, v[0].y, v[0].z, v[0].w};
    float bv[4] = {v[1].x, v[1].y, v[1].z, v[1].w};
#pragma unroll
    for (int c = 0; c < 4; ++c) {
        hi[(4 * eq + c) * LDSTP + sp] = bf16_rne(av[c]) | (bf16_rne(bv[c]) << 16);
    }
}

__device__ __forceinline__ bf16x8 read_frag_pad(const unsigned* buf, int row, int q) {
    return *(const bf16x8*)(buf + row * LDSTP + 4 * q);
}

// ---------------------------------------------------------------------------
// MFMA cores (all single-bf16)
// ---------------------------------------------------------------------------
__device__ __forceinline__ void mfma_ss1_64(const u16* Ah, const u16* Bh,
                                            f32x4 acc[2][2], int tid) {
    const int lane = tid & 63, w = tid >> 6;
    const int wm = (w & 1) * 32, wn = (w >> 1) * 32;
    const int fr = lane & 15, q = lane >> 4;
    bf16x8 ah[2];
#pragma unroll
    for (int i = 0; i < 2; ++i) ah[i] = read_frag_sw(Ah, wm + 16 * i + fr, q);
#pragma unroll
    for (int j = 0; j < 2; ++j) {
        bf16x8 bh = read_frag_sw(Bh, wn + 16 * j + fr, q);
#pragma unroll
        for (int i = 0; i < 2; ++i)
            acc[i][j] = __builtin_amdgcn_mfma_f32_16x16x32_bf16(ah[i], bh, acc[i][j], 0, 0, 0);
    }
}

__device__ __forceinline__ void mfma_sbp1_64(const u16* Ah, const unsigned* Bh,
                                             f32x4 acc[2][2], int tid) {
    const int lane = tid & 63, w = tid >> 6;
    const int wm = (w & 1) * 32, wn = (w >> 1) * 32;
    const int fr = lane & 15, q = lane >> 4;
    bf16x8 ah[2];
#pragma unroll
    for (int i = 0; i < 2; ++i) ah[i] = read_frag_sw(Ah, wm + 16 * i + fr, q);
#pragma unroll
    for (int j = 0; j < 2; ++j) {
        bf16x8 bh = read_frag_pad(Bh, wn + 16 * j + fr, q);
#pragma unroll
        for (int i = 0; i < 2; ++i)
            acc[i][j] = __builtin_amdgcn_mfma_f32_16x16x32_bf16(ah[i], bh, acc[i][j], 0, 0, 0);
    }
}

__device__ __forceinline__ void mfma_sp1(const u16* Ah, const unsigned* Bh,
                                         f32x4 acc[4][2], int tid) {
    const int lane = tid & 63, w = tid >> 6;
    const int wm = (w & 1) * 64, wn = (w >> 1) * 32;
    const int fr = lane & 15, q = lane >> 4;
    bf16x8 ah[4];
#pragma unroll
    for (int i = 0; i < 4; ++i) ah[i] = read_frag_sw(Ah, wm + 16 * i + fr, q);
#pragma unroll
    for (int j = 0; j < 2; ++j) {
        bf16x8 bh = read_frag_pad(Bh, wn + 16 * j + fr, q);
#pragma unroll
        for (int i = 0; i < 4; ++i)
            acc[i][j] = __builtin_amdgcn_mfma_f32_16x16x32_bf16(ah[i], bh, acc[i][j], 0, 0, 0);
    }
}

__device__ __forceinline__ void mfma_s1(const u16* Ah, const u16* Bh,
                                        f32x4 acc[4][2], int tid) {
    const int lane = tid & 63, w = tid >> 6;
    const int wm = (w & 1) * 64, wn = (w >> 1) * 32;
    const int fr = lane & 15, q = lane >> 4;
    bf16x8 ah[4];
#pragma unroll
    for (int i = 0; i < 4; ++i) ah[i] = read_frag_sw(Ah, wm + 16 * i + fr, q);
#pragma unroll
    for (int j = 0; j < 2; ++j) {
        bf16x8 bh = read_frag_sw(Bh, wn + 16 * j + fr, q);
#pragma unroll
        for (int i = 0; i < 4; ++i)
            acc[i][j] = __builtin_amdgcn_mfma_f32_16x16x32_bf16(ah[i], bh, acc[i][j], 0, 0, 0);
    }
}

// ---------------------------------------------------------------------------
// Convert kernels
// ---------------------------------------------------------------------------
__global__ __launch_bounds__(256) void k_conv1(const float* __restrict__ src,
                                               u16* __restrict__ hi) {
    const int i = blockIdx.x * 256 + threadIdx.x;
    float4 v = ((const float4*)src)[i];
    ((ushort4*)hi)[i] = make_ushort4((u16)bf16_rne(v.x), (u16)bf16_rne(v.y),
                                     (u16)bf16_rne(v.z), (u16)bf16_rne(v.w));
}

// Wo [1536,512] -> WoT hi plane [512,1536]
__global__ __launch_bounds__(256) void k_wot(const float* __restrict__ Wo,
                                             u16* __restrict__ thi) {
    __shared__ float t[64][65];
    const int tid = threadIdx.x;
    const int r0 = blockIdx.x * 64;
    const int c0 = blockIdx.y * 64;
    const int rr = tid >> 4, cc = tid & 15;
#pragma unroll
    for (int i = 0; i < 4; ++i) {
        float4 v = *(const float4*)(Wo + (size_t)(r0 + rr + 16 * i) * DDIM + c0 + 4 * cc);
        t[rr + 16 * i][4 * cc + 0] = v.x;
        t[rr + 16 * i][4 * cc + 1] = v.y;
        t[rr + 16 * i][4 * cc + 2] = v.z;
        t[rr + 16 * i][4 * cc + 3] = v.w;
    }
    __syncthreads();
#pragma unroll
    for (int i = 0; i < 4; ++i) {
        const int oc = rr + 16 * i;
        size_t off = (size_t)(c0 + oc) * (EE + DDIM) + r0 + 4 * cc;
        *(ushort4*)(thi + off) = make_ushort4((u16)bf16_rne(t[4 * cc + 0][oc]),
                                              (u16)bf16_rne(t[4 * cc + 1][oc]),
                                              (u16)bf16_rne(t[4 * cc + 2][oc]),
                                              (u16)bf16_rne(t[4 * cc + 3][oc]));
    }
}

// ---------------------------------------------------------------------------
// K1: decW = dec @ W_attn^T. Pure-glds, counted-vmcnt pipeline.
// Per-wave 4 vmem/tile -> entry wait vmcnt(4). NT = 8.
// ---------------------------------------------------------------------------
__global__ __launch_bounds__(256) void k_decw(const u16* __restrict__ Ahp,
                                              const u16* __restrict__ Bhp,
                                              u16* __restrict__ Chi) {
    __shared__ u16 Ah[2][2 * BM2 * ROWU], Bh[2][2 * BN * ROWU];
    const int tid = threadIdx.x;
    const int bm = blockIdx.x * BM2, bn = blockIdx.y * BN;
    const u16* As = Ahp + (size_t)bm * DDIM;
    const u16* Bs = Bhp + (size_t)bn * DDIM;
    f32x4 acc[2][2] = {};
    const int NT = DDIM / (2 * BK);  // 8

    // prologue: stage tile 0
    stage_glds<BM2>(&Ah[0][0], As, DDIM, tid);
    stage_glds<BM2>(&Ah[0][BM2 * ROWU], As + BK, DDIM, tid);
    stage_glds<BN>(&Bh[0][0], Bs, DDIM, tid);
    stage_glds<BN>(&Bh[0][BN * ROWU], Bs + BK, DDIM, tid);

    for (int t = 0; t < NT - 1; ++t) {
        const int k1 = (t + 1) * 2 * BK;
        const int bf = (t + 1) & 1;
        stage_glds<BM2>(&Ah[bf][0], As + k1, DDIM, tid);
        stage_glds<BM2>(&Ah[bf][BM2 * ROWU], As + k1 + BK, DDIM, tid);
        stage_glds<BN>(&Bh[bf][0], Bs + k1, DDIM, tid);
        stage_glds<BN>(&Bh[bf][BN * ROWU], Bs + k1 + BK, DDIM, tid);
        WAITVM(4);  // tile t's loads done; t+1's 4 stay in flight
        SBAR();
        const u16* a = Ah[t & 1];
        const u16* b = Bh[t & 1];
        mfma_ss1_64(a, b, acc, tid);
        mfma_ss1_64(a + BM2 * ROWU, b + BN * ROWU, acc, tid);
        SBAR();
    }
    WAITVM(0);
    SBAR();
    {
        const u16* a = Ah[(NT - 1) & 1];
        const u16* b = Bh[(NT - 1) & 1];
        mfma_ss1_64(a, b, acc, tid);
        mfma_ss1_64(a + BM2 * ROWU, b + BN * ROWU, acc, tid);
    }
    const int lane = tid & 63, w = tid >> 6;
    const int wm = (w & 1) * 32, wn = (w >> 1) * 32;
    const int fr = lane & 15, q = lane >> 4;
#pragma unroll
    for (int j = 0; j < 2; ++j) {
        const int col = bn + wn + 16 * j + fr;
#pragma unroll
        for (int i = 0; i < 2; ++i)
#pragma unroll
            for (int r = 0; r < 4; ++r) {
                const int row = bm + wm + 16 * i + 4 * q + r;
                Chi[(size_t)row * EE + col] = (u16)bf16_rne(acc[i][j][r]);
            }
    }
}

// ---------------------------------------------------------------------------
// K1b: decb[m] = dec[m,:] . b_attn
// ---------------------------------------------------------------------------
__global__ __launch_bounds__(256) void k_decb(const float* __restrict__ dec,
                                              const float* __restrict__ ba,
                                              float* __restrict__ decb) {
    const int row = blockIdx.x * 4 + (threadIdx.x >> 6);
    const int lane = threadIdx.x & 63;
    const float* x = dec + (size_t)row * DDIM;
    float s = 0.f;
#pragma unroll
    for (int i = 0; i < 8; ++i) {
        int idx = lane + i * 64;
        s += x[idx] * ba[idx];
    }
#pragma unroll
    for (int off = 32; off >= 1; off >>= 1) s += __shfl_xor(s, off, 64);
    if (lane == 0) decb[row] = s;
}

// ---------------------------------------------------------------------------
// K2: masked energies. A (decW) glds; B (enc fp32) T14 split: load regs at
// loop top, pack after MFMA. Entry wait vmcnt(6) = t+1's (4 B-loads + 2 glds).
// NT = 16.
// ---------------------------------------------------------------------------
__global__ __launch_bounds__(256) void k_energy(const u16* __restrict__ Ahp,
                                                const float* __restrict__ enc,
                                                const int* __restrict__ mask,
                                                const float* __restrict__ decb,
                                                float* __restrict__ menerg) {
    const int b = blockIdx.z;
    const int bn = blockIdx.x * BN;
    const int bm = blockIdx.y * BM2;
    __shared__ u16 Ah[2][2 * BM2 * ROWU];
    __shared__ unsigned Bp[2][2 * BN * LDSTP];
    const int tid = threadIdx.x;
    const u16* Abh = Ahp + (size_t)b * TT * EE + (size_t)bm * EE;
    const float* Bt = enc + (size_t)b * SS * EE + (size_t)bn * EE;
    f32x4 acc[2][2] = {};
    float4 bv[4];
    const int NT = EE / (2 * BK);  // 16

    // prologue: tile 0 — B loads first (so compiler pack-wait is counted, not drain)
    nt_load(&bv[0], Bt, EE, tid);
    nt_load(&bv[2], Bt + BK, EE, tid);
    stage_glds<BM2>(&Ah[0][0], Abh, EE, tid);
    stage_glds<BM2>(&Ah[0][BM2 * ROWU], Abh + BK, EE, tid);
    nt_pack(&Bp[0][0], &bv[0], tid);
    nt_pack(&Bp[0][BN * LDSTP], &bv[2], tid);
    WAITLGKM();

    for (int t = 0; t < NT - 1; ++t) {
        const int k1 = (t + 1) * 2 * BK;
        const int bf = (t + 1) & 1;
        nt_load(&bv[0], Bt + k1, EE, tid);
        nt_load(&bv[2], Bt + k1 + BK, EE, tid);
        stage_glds<BM2>(&Ah[bf][0], Abh + k1, EE, tid);
        stage_glds<BM2>(&Ah[bf][BM2 * ROWU], Abh + k1 + BK, EE, tid);
        WAITVM(6);  // tile t's glds done; t+1's 6 in flight
        SBAR();
        const u16* a = Ah[t & 1];
        const unsigned* bb = Bp[t & 1];
        mfma_sbp1_64(a, bb, acc, tid);
        mfma_sbp1_64(a + BM2 * ROWU, bb + BN * LDSTP, acc, tid);
        __builtin_amdgcn_sched_barrier(0);
        nt_pack(&Bp[bf][0], &bv[0], tid);       // compiler waits vmcnt(2) here
        nt_pack(&Bp[bf][BN * LDSTP], &bv[2], tid);
        WAITLGKM();
        SBAR();
    }
    WAITVM(0);
    SBAR();
    {
        const u16* a = Ah[(NT - 1) & 1];
        const unsigned* bb = Bp[(NT - 1) & 1];
        mfma_sbp1_64(a, bb, acc, tid);
        mfma_sbp1_64(a + BM2 * ROWU, bb + BN * LDSTP, acc, tid);
    }
    const int lane = tid & 63, w = tid >> 6;
    const int wm = (w & 1) * 32, wn = (w >> 1) * 32;
    const int fr = lane & 15, q = lane >> 4;
    const int* mb = mask + (size_t)b * SS;
    const float* dbp = decb + (size_t)b * TT + bm;
    float* Crow = menerg + (size_t)b * TT * SS + (size_t)bm * SS;
    float db[2][4];
#pragma unroll
    for (int i = 0; i < 2; ++i) {
        float4 d4 = *(const float4*)(dbp + wm + 16 * i + 4 * q);
        db[i][0] = d4.x; db[i][1] = d4.y; db[i][2] = d4.z; db[i][3] = d4.w;
    }
#pragma unroll
    for (int j = 0; j < 2; ++j) {
        const int col = bn + wn + 16 * j + fr;
        const int mk = mb[col];
#pragma unroll
        for (int i = 0; i < 2; ++i)
#pragma unroll
            for (int r = 0; r < 4; ++r) {
                const int row = wm + 16 * i + 4 * q + r;
                Crow[(size_t)row * SS + col] = mk ? acc[i][j][r] + db[i][r] : NEG_INF_F;
            }
    }
}

// ---------------------------------------------------------------------------
// K3: softmax over S=512 -> attn fp32 + attn hi plane
// ---------------------------------------------------------------------------
__global__ __launch_bounds__(128) void k_softmax(const float* __restrict__ me,
                                                 float* __restrict__ attn,
                                                 u16* __restrict__ ahi) {
    const int row = blockIdx.x;
    const int tid = threadIdx.x;
    const float4 v = ((const float4*)(me + (size_t)row * SS))[tid];
    float m = fmaxf(fmaxf(v.x, v.y), fmaxf(v.z, v.w));
#pragma unroll
    for (int off = 32; off >= 1; off >>= 1) m = fmaxf(m, __shfl_xor(m, off, 64));
    __shared__ float redm[2];
    __shared__ float reds[2];
    const int wv = tid >> 6, lane = tid & 63;
    if (lane == 0) redm[wv] = m;
    __syncthreads();
    m = fmaxf(redm[0], redm[1]);
    float e0 = __expf(v.x - m), e1 = __expf(v.y - m);
    float e2 = __expf(v.z - m), e3 = __expf(v.w - m);
    float s = (e0 + e1) + (e2 + e3);
#pragma unroll
    for (int off = 32; off >= 1; off >>= 1) s += __shfl_xor(s, off, 64);
    if (lane == 0) reds[wv] = s;
    __syncthreads();
    s = reds[0] + reds[1];
    const float inv = 1.0f / s;
    float o0 = e0 * inv, o1 = e1 * inv, o2 = e2 * inv, o3 = e3 * inv;
    ((float4*)(attn + (size_t)row * SS))[tid] = make_float4(o0, o1, o2, o3);
    ((ushort4*)(ahi + (size_t)row * SS))[tid] =
        make_ushort4((u16)bf16_rne(o0), (u16)bf16_rne(o1),
                     (u16)bf16_rne(o2), (u16)bf16_rne(o3));
}

// ---------------------------------------------------------------------------
// K4: wc = attn @ enc. A (attn) glds; B (enc^T) T14 split. Entry wait
// vmcnt(8) = t+1's (4 B-loads + 4 glds). NT = 8.
// ---------------------------------------------------------------------------
__global__ __launch_bounds__(256) void k_ctx(const u16* __restrict__ Ahp,
                                             const float* __restrict__ enc,
                                             u16* __restrict__ Chi) {
    const int b = blockIdx.z;
    const int bn = blockIdx.x * BN;  // over E
    __shared__ u16 Ah[2][2 * BM * ROWU];
    __shared__ unsigned Bp[2][2 * BN * LDSTP];
    const int tid = threadIdx.x;
    const u16* Abh = Ahp + (size_t)b * TT * SS;
    const float* Bm = enc + (size_t)b * SS * EE + bn;
    f32x4 acc[4][2] = {};
    float4 bv0[2], bv1[2];
    const int NT = SS / (2 * BK);  // 8

    // prologue
    tr_load(bv0, Bm, EE, tid);
    tr_load(bv1, Bm + (size_t)BK * EE, EE, tid);
    stage_glds<BM>(&Ah[0][0], Abh, SS, tid);
    stage_glds<BM>(&Ah[0][BM * ROWU], Abh + BK, SS, tid);
    tr_pack(&Bp[0][0], bv0, tid);
    tr_pack(&Bp[0][BN * LDSTP], bv1, tid);
    WAITLGKM();

    for (int t = 0; t < NT - 1; ++t) {
        const int k1 = (t + 1) * 2 * BK;
        const int bf = (t + 1) & 1;
        tr_load(bv0, Bm + (size_t)k1 * EE, EE, tid);
        tr_load(bv1, Bm + (size_t)(k1 + BK) * EE, EE, tid);
        stage_glds<BM>(&Ah[bf][0], Abh + k1, SS, tid);
        stage_glds<BM>(&Ah[bf][BM * ROWU], Abh + k1 + BK, SS, tid);
        WAITVM(8);
        SBAR();
        const u16* a = Ah[t & 1];
        const unsigned* bb = Bp[t & 1];
        mfma_sp1(a, bb, acc, tid);
        mfma_sp1(a + BM * ROWU, bb + BN * LDSTP, acc, tid);
        __builtin_amdgcn_sched_barrier(0);
        tr_pack(&Bp[bf][0], bv0, tid);
        tr_pack(&Bp[bf][BN * LDSTP], bv1, tid);
        WAITLGKM();
        SBAR();
    }
    WAITVM(0);
    SBAR();
    {
        const u16* a = Ah[(NT - 1) & 1];
        const unsigned* bb = Bp[(NT - 1) & 1];
        mfma_sp1(a, bb, acc, tid);
        mfma_sp1(a + BM * ROWU, bb + BN * LDSTP, acc, tid);
    }
    const int lane = tid & 63, w = tid >> 6;
    const int wm = (w & 1) * 64, wn = (w >> 1) * 32;
    const int fr = lane & 15, q = lane >> 4;
    u16* Ch = Chi + (size_t)b * TT * EE;
#pragma unroll
    for (int j = 0; j < 2; ++j) {
        const int col = bn + wn + 16 * j + fr;
#pragma unroll
        for (int i = 0; i < 4; ++i)
#pragma unroll
            for (int r = 0; r < 4; ++r) {
                const int row = wm + 16 * i + 4 * q + r;
                Ch[(size_t)row * EE + col] = (u16)bf16_rne(acc[i][j][r]);
            }
    }
}

// ---------------------------------------------------------------------------
// K5: h_tilde = tanh([wc | dec] @ W_out). Pure-glds, counted vmcnt(6). NT=24.
// ---------------------------------------------------------------------------
__global__ __launch_bounds__(256) void k_out(const u16* __restrict__ wch,
                                             const u16* __restrict__ dech,
                                             const u16* __restrict__ woth,
                                             float* __restrict__ ht) {
    __shared__ u16 Ah[2][2 * BM * ROWU], Bh[2][2 * BN * ROWU];
    const int tid = threadIdx.x;
    const int bm = blockIdx.x * BM, bn = blockIdx.y * BN;
    const int KTOT = EE + DDIM;
    f32x4 acc[4][2] = {};
    const int NT = KTOT / (2 * BK);  // 24

    auto STG = [&](int k0, int bf) {
#pragma unroll
        for (int s = 0; s < 2; ++s) {
            const int kk = k0 + BK * s;
            const u16* ah;
            int ld;
            if (kk < EE) {
                ah = wch + (size_t)bm * EE + kk;
                ld = EE;
            } else {
                ah = dech + (size_t)bm * DDIM + (kk - EE);
                ld = DDIM;
            }
            stage_glds<BM>(&Ah[bf][s * BM * ROWU], ah, ld, tid);
            stage_glds<BN>(&Bh[bf][s * BN * ROWU], woth + (size_t)bn * KTOT + kk, KTOT, tid);
        }
    };

    STG(0, 0);
    for (int t = 0; t < NT - 1; ++t) {
        STG((t + 1) * 2 * BK, (t + 1) & 1);
        WAITVM(6);
        SBAR();
        const u16* a = Ah[t & 1];
        const u16* b = Bh[t & 1];
        mfma_s1(a, b, acc, tid);
        mfma_s1(a + BM * ROWU, b + BN * ROWU, acc, tid);
        SBAR();
    }
    WAITVM(0);
    SBAR();
    {
        const u16* a = Ah[(NT - 1) & 1];
        const u16* b = Bh[(NT - 1) & 1];
        mfma_s1(a, b, acc, tid);
        mfma_s1(a + BM * ROWU, b + BN * ROWU, acc, tid);
    }
    const int lane = tid & 63, w = tid >> 6;
    const int wm = (w & 1) * 64, wn = (w >> 1) * 32;
    const int fr = lane & 15, q = lane >> 4;
#pragma unroll
    for (int j = 0; j < 2; ++j) {
        const int col = bn + wn + 16 * j + fr;
#pragma unroll
        for (int i = 0; i < 4; ++i)
#pragma unroll
            for (int r = 0; r < 4; ++r) {
                const int row = bm + wm + 16 * i + 4 * q + r;
                ht[(size_t)row * DDIM + col] = fast_tanh(acc[i][j][r]);
            }
    }
}

// ---------------------------------------------------------------------------
extern "C" void kernel_launch(void* const* d_in, const int* in_sizes, int n_in,
                              void* d_out, int out_size, void* d_ws, size_t ws_size,
                              hipStream_t stream) {
    (void)in_sizes; (void)n_in; (void)out_size; (void)ws_size;
    const float* dec = (const float*)d_in[0];
    const float* enc = (const float*)d_in[1];
    const int* mask = (const int*)d_in[2];
    const float* Wa = (const float*)d_in[3];
    const float* ba = (const float*)d_in[4];
    const float* Wo = (const float*)d_in[5];

    float* h_tilde = (float*)d_out;
    float* attn = h_tilde + (size_t)BB * TT * DDIM;
    float* menerg = attn + (size_t)BB * TT * SS;

    // Workspace layout (bytes)
    char* ws = (char*)d_ws;
    u16* decW_hi = (u16*)(ws);                       // 8192x1024 u16 = 16.78 MB
    u16* dec_hi  = (u16*)(ws + 33554432);            // 8192x512
    u16* attn_hi = (u16*)(ws + 50331648);            // 8192x512
    u16* wa_hi   = (u16*)(ws + 67108864);            // 1024x512
    u16* wot_hi  = (u16*)(ws + 69206016);            // 512x1536
    float* decb  = (float*)(ws + 72351744);          // 8192 f32
    // wc plane aliases decW_hi (decW dead after k_energy)
    u16* wc_hi = decW_hi;

    k_conv1<<<(BB * TT * DDIM) / 4 / 256, 256, 0, stream>>>(dec, dec_hi);
    k_conv1<<<(EE * DDIM) / 4 / 256, 256, 0, stream>>>(Wa, wa_hi);
    k_wot<<<dim3((EE + DDIM) / 64, DDIM / 64), 256, 0, stream>>>(Wo, wot_hi);
    k_decb<<<(BB * TT) / 4, 256, 0, stream>>>(dec, ba, decb);
    k_decw<<<dim3((BB * TT) / BM2, EE / BN), 256, 0, stream>>>(dec_hi, wa_hi, decW_hi);
    k_energy<<<dim3(SS / BN, TT / BM2, BB), 256, 0, stream>>>(decW_hi, enc, mask, decb, menerg);
    k_softmax<<<BB * TT, 128, 0, stream>>>(menerg, attn, attn_hi);
    k_ctx<<<dim3(EE / BN, 1, BB), 256, 0, stream>>>(attn_hi, enc, wc_hi);
    k_out<<<dim3((BB * TT) / BM, DDIM / BN), 256, 0, stream>>>(wc_hi, dec_hi, wot_hi, h_tilde);
}

// Round 9
// 328.254 us; speedup vs baseline: 1.0112x; 1.0112x over previous
//
#include <hip/hip_runtime.h>
#include <cmath>

// Problem constants
#define BB 64
#define TT 128
#define SS 512
#define EE 1024
#define DDIM 512
#define NEG_INF_F (-1.0e10f)

// MFMA tiling
#define BM2 64     // block row count for the GEMM kernels (wave tile 32 rows)
#define BN 64      // block col count (k_decw, k_ctx, k_out)
#define BNE 32     // block col count for k_energy (grid 2048 -> 8 blk/CU)
#define BK 32
#define LDSTP 20   // padded layout row stride (dwords)
#define ROWU 32    // swizzled plane layout row stride in u16 (64 B/row)

typedef unsigned short u16;
typedef __attribute__((ext_vector_type(8))) short bf16x8;
typedef __attribute__((ext_vector_type(4))) float f32x4;

// ---------------------------------------------------------------------------
__device__ __forceinline__ unsigned bf16_rne(float f) {
    unsigned u = __float_as_uint(f);
    return (u + 0x7fffu + ((u >> 16) & 1u)) >> 16;
}

// Overflow-safe fast tanh
__device__ __forceinline__ float fast_tanh(float x) {
    float t = __expf(-2.0f * fabsf(x));
    float r = __fdividef(1.0f - t, 1.0f + t);
    return copysignf(r, x);
}

// ---------------------------------------------------------------------------
// glds staging of a bf16 plane tile: ROWS rows x 32 bf16, quad-swizzled.
// ---------------------------------------------------------------------------
template <int ROWS>
__device__ __forceinline__ void stage_glds(u16* lds, const u16* __restrict__ src,
                                           int ld, int tid) {
    const int w = tid >> 6, lane = tid & 63;
    const int rl = lane >> 2, p = lane & 3;
#pragma unroll
    for (int i = 0; i < ROWS / 64; ++i) {
        const int r0 = (w + 4 * i) * 16;
        const int r = r0 + rl;
        const int q = p ^ ((r >> 1) & 3);
        const u16* g = src + (size_t)r * ld + 8 * q;
        __builtin_amdgcn_global_load_lds(
            (const __attribute__((address_space(1))) unsigned*)g,
            (__attribute__((address_space(3))) unsigned*)(lds + r0 * ROWU),
            16, 0, 0);
    }
}

__device__ __forceinline__ bf16x8 read_frag_sw(const u16* buf, int row, int q) {
    const int c = q ^ ((row >> 1) & 3);
    return *(const bf16x8*)(buf + row * ROWU + 8 * c);
}

// ---------------------------------------------------------------------------
// Single-plane VALU staging of an NT fp32 operand (ROWS x 32 k) into padded
// LDS (u32 = bf16 pair), rne only. ROWS=32: one float4 per thread.
// ---------------------------------------------------------------------------
template <int ROWS>
__device__ __forceinline__ void stage_nt1(unsigned* hi,
                                          const float* __restrict__ src, int ld, int tid) {
#pragma unroll
    for (int i = 0; i < ROWS / 32; ++i) {
        int s = tid + 256 * i;
        int r = s >> 3, kq = s & 7;
        float4 v = *(const float4*)(src + (size_t)r * ld + 4 * kq);
        *(uint2*)&hi[r * LDSTP + 2 * kq] =
            make_uint2(bf16_rne(v.x) | (bf16_rne(v.y) << 16),
                       bf16_rne(v.z) | (bf16_rne(v.w) << 16));
    }
}

// ---------------------------------------------------------------------------
// Single-plane staging of transposed fp32 B tile (k_ctx): [32 k][64 n] -> rows=n
// ---------------------------------------------------------------------------
__device__ __forceinline__ void stage_tr1(unsigned* hi, const float* __restrict__ src,
                                          int ld, int tid) {
    int eq = tid & 15;   // n quad
    int sp = tid >> 4;   // k pair
    const float* p = src + (size_t)(2 * sp) * ld + 4 * eq;
    float4 va = *(const float4*)p;
    float4 vb = *(const float4*)(p + ld);
    float av[4] = {va.x, va.y, va.z, va.w};
    float bv[4] = {vb.x, vb.y, vb.z, vb.w};
#pragma unroll
    for (int c = 0; c < 4; ++c) {
        hi[(4 * eq + c) * LDSTP + sp] = bf16_rne(av[c]) | (bf16_rne(bv[c]) << 16);
    }
}

__device__ __forceinline__ bf16x8 read_frag_pad(const unsigned* buf, int row, int q) {
    return *(const bf16x8*)(buf + row * LDSTP + 4 * q);
}

// ---------------------------------------------------------------------------
// MFMA cores (all single-bf16). 64-row blocks, wave grid 2x2.
// ---------------------------------------------------------------------------
// 64x64, A sw x B sw (k_decw, k_out): wave tile 32x32, acc[2][2]
__device__ __forceinline__ void mfma_ss1_64(const u16* Ah, const u16* Bh,
                                            f32x4 acc[2][2], int tid) {
    const int lane = tid & 63, w = tid >> 6;
    const int wm = (w & 1) * 32, wn = (w >> 1) * 32;
    const int fr = lane & 15, q = lane >> 4;
    bf16x8 ah[2];
#pragma unroll
    for (int i = 0; i < 2; ++i) ah[i] = read_frag_sw(Ah, wm + 16 * i + fr, q);
#pragma unroll
    for (int j = 0; j < 2; ++j) {
        bf16x8 bh = read_frag_sw(Bh, wn + 16 * j + fr, q);
#pragma unroll
        for (int i = 0; i < 2; ++i)
            acc[i][j] = __builtin_amdgcn_mfma_f32_16x16x32_bf16(ah[i], bh, acc[i][j], 0, 0, 0);
    }
}

// 64x64, A sw x B padded (k_ctx): wave tile 32x32, acc[2][2]
__device__ __forceinline__ void mfma_sbp1_64(const u16* Ah, const unsigned* Bh,
                                             f32x4 acc[2][2], int tid) {
    const int lane = tid & 63, w = tid >> 6;
    const int wm = (w & 1) * 32, wn = (w >> 1) * 32;
    const int fr = lane & 15, q = lane >> 4;
    bf16x8 ah[2];
#pragma unroll
    for (int i = 0; i < 2; ++i) ah[i] = read_frag_sw(Ah, wm + 16 * i + fr, q);
#pragma unroll
    for (int j = 0; j < 2; ++j) {
        bf16x8 bh = read_frag_pad(Bh, wn + 16 * j + fr, q);
#pragma unroll
        for (int i = 0; i < 2; ++i)
            acc[i][j] = __builtin_amdgcn_mfma_f32_16x16x32_bf16(ah[i], bh, acc[i][j], 0, 0, 0);
    }
}

// 64x32 (k_energy): wave tile 32 rows x 16 cols, acc[2] (i-frags), 1 j-frag
__device__ __forceinline__ void mfma_e(const u16* Ah, const unsigned* Bh,
                                       f32x4 acc[2], int tid) {
    const int lane = tid & 63, w = tid >> 6;
    const int wm = (w & 1) * 32, wn = (w >> 1) * 16;
    const int fr = lane & 15, q = lane >> 4;
    bf16x8 bh = read_frag_pad(Bh, wn + fr, q);
#pragma unroll
    for (int i = 0; i < 2; ++i) {
        bf16x8 ah = read_frag_sw(Ah, wm + 16 * i + fr, q);
        acc[i] = __builtin_amdgcn_mfma_f32_16x16x32_bf16(ah, bh, acc[i], 0, 0, 0);
    }
}

// ---------------------------------------------------------------------------
// Convert / prep kernels
// ---------------------------------------------------------------------------
// fp32 -> single bf16 hi plane (Wa)
__global__ __launch_bounds__(256) void k_conv1(const float* __restrict__ src,
                                               u16* __restrict__ hi) {
    const int i = blockIdx.x * 256 + threadIdx.x;
    float4 v = ((const float4*)src)[i];
    ((ushort4*)hi)[i] = make_ushort4((u16)bf16_rne(v.x), (u16)bf16_rne(v.y),
                                     (u16)bf16_rne(v.z), (u16)bf16_rne(v.w));
}

// Fused: dec -> dec_hi bf16 plane AND decb[m] = dec[m,:].b_attn (one dec read)
__global__ __launch_bounds__(256) void k_prep(const float* __restrict__ dec,
                                              const float* __restrict__ ba,
                                              u16* __restrict__ dec_hi,
                                              float* __restrict__ decb) {
    const int row = blockIdx.x * 4 + (threadIdx.x >> 6);
    const int lane = threadIdx.x & 63;
    const float4* x4 = (const float4*)(dec + (size_t)row * DDIM);
    const float4* b4 = (const float4*)ba;
    ushort4* h4 = (ushort4*)(dec_hi + (size_t)row * DDIM);
    float s = 0.f;
#pragma unroll
    for (int i = 0; i < 2; ++i) {
        const int idx = lane + 64 * i;
        float4 v = x4[idx];
        float4 bb = b4[idx];
        s += v.x * bb.x + v.y * bb.y + v.z * bb.z + v.w * bb.w;
        h4[idx] = make_ushort4((u16)bf16_rne(v.x), (u16)bf16_rne(v.y),
                               (u16)bf16_rne(v.z), (u16)bf16_rne(v.w));
    }
#pragma unroll
    for (int off = 32; off >= 1; off >>= 1) s += __shfl_xor(s, off, 64);
    if (lane == 0) decb[row] = s;
}

// Wo [1536,512] -> WoT hi plane [512,1536]
__global__ __launch_bounds__(256) void k_wot(const float* __restrict__ Wo,
                                             u16* __restrict__ thi) {
    __shared__ float t[64][65];
    const int tid = threadIdx.x;
    const int r0 = blockIdx.x * 64;
    const int c0 = blockIdx.y * 64;
    const int rr = tid >> 4, cc = tid & 15;
#pragma unroll
    for (int i = 0; i < 4; ++i) {
        float4 v = *(const float4*)(Wo + (size_t)(r0 + rr + 16 * i) * DDIM + c0 + 4 * cc);
        t[rr + 16 * i][4 * cc + 0] = v.x;
        t[rr + 16 * i][4 * cc + 1] = v.y;
        t[rr + 16 * i][4 * cc + 2] = v.z;
        t[rr + 16 * i][4 * cc + 3] = v.w;
    }
    __syncthreads();
#pragma unroll
    for (int i = 0; i < 4; ++i) {
        const int oc = rr + 16 * i;
        size_t off = (size_t)(c0 + oc) * (EE + DDIM) + r0 + 4 * cc;
        *(ushort4*)(thi + off) = make_ushort4((u16)bf16_rne(t[4 * cc + 0][oc]),
                                              (u16)bf16_rne(t[4 * cc + 1][oc]),
                                              (u16)bf16_rne(t[4 * cc + 2][oc]),
                                              (u16)bf16_rne(t[4 * cc + 3][oc]));
    }
}

// ---------------------------------------------------------------------------
// K1: decW = dec @ W_attn^T (all-single bf16). 64x64 block, BK=64 subtiles.
// Grid (128, 16) = 2048 -> ~5 blk/CU (LDS 32 KB).
// ---------------------------------------------------------------------------
__global__ __launch_bounds__(256) void k_decw(const u16* __restrict__ Ahp,
                                              const u16* __restrict__ Bhp,
                                              u16* __restrict__ Chi) {
    __shared__ u16 Ah[2][BM2 * ROWU], Bh[2][BN * ROWU];
    const int tid = threadIdx.x;
    const int bm = blockIdx.x * BM2, bn = blockIdx.y * BN;
    f32x4 acc[2][2] = {};
    for (int k0 = 0; k0 < DDIM; k0 += 2 * BK) {
        __syncthreads();
        stage_glds<BM2>(Ah[0], Ahp + (size_t)bm * DDIM + k0, DDIM, tid);
        stage_glds<BM2>(Ah[1], Ahp + (size_t)bm * DDIM + k0 + BK, DDIM, tid);
        stage_glds<BN>(Bh[0], Bhp + (size_t)bn * DDIM + k0, DDIM, tid);
        stage_glds<BN>(Bh[1], Bhp + (size_t)bn * DDIM + k0 + BK, DDIM, tid);
        __builtin_amdgcn_s_waitcnt(0);
        __syncthreads();
        mfma_ss1_64(Ah[0], Bh[0], acc, tid);
        mfma_ss1_64(Ah[1], Bh[1], acc, tid);
    }
    const int lane = tid & 63, w = tid >> 6;
    const int wm = (w & 1) * 32, wn = (w >> 1) * 32;
    const int fr = lane & 15, q = lane >> 4;
#pragma unroll
    for (int j = 0; j < 2; ++j) {
        const int col = bn + wn + 16 * j + fr;
#pragma unroll
        for (int i = 0; i < 2; ++i)
#pragma unroll
            for (int r = 0; r < 4; ++r) {
                const int row = bm + wm + 16 * i + 4 * q + r;
                Chi[(size_t)row * EE + col] = (u16)bf16_rne(acc[i][j][r]);
            }
    }
}

// ---------------------------------------------------------------------------
// K2: masked energies. decW single (glds) x enc single (stage_nt1).
// BN=32 -> grid (16, 2, 64) = 2048 -> 8 blk/CU (LDS ~13 KB). BK=64 subtiles.
// ---------------------------------------------------------------------------
__global__ __launch_bounds__(256) void k_energy(const u16* __restrict__ Ahp,
                                                const float* __restrict__ enc,
                                                const int* __restrict__ mask,
                                                const float* __restrict__ decb,
                                                float* __restrict__ menerg) {
    const int b = blockIdx.z;
    const int bn = blockIdx.x * BNE;
    const int bm = blockIdx.y * BM2;
    __shared__ u16 Ah[2][BM2 * ROWU];
    __shared__ unsigned Bp[2][BNE * LDSTP];
    const int tid = threadIdx.x;
    const u16* Abh = Ahp + (size_t)b * TT * EE + (size_t)bm * EE;
    const float* Bt = enc + (size_t)b * SS * EE + (size_t)bn * EE;
    f32x4 acc[2] = {};
    for (int k0 = 0; k0 < EE; k0 += 2 * BK) {
        __syncthreads();
        stage_glds<BM2>(Ah[0], Abh + k0, EE, tid);
        stage_glds<BM2>(Ah[1], Abh + k0 + BK, EE, tid);
        stage_nt1<BNE>(Bp[0], Bt + k0, EE, tid);
        stage_nt1<BNE>(Bp[1], Bt + k0 + BK, EE, tid);
        __builtin_amdgcn_s_waitcnt(0);
        __syncthreads();
        mfma_e(Ah[0], Bp[0], acc, tid);
        mfma_e(Ah[1], Bp[1], acc, tid);
    }
    const int lane = tid & 63, w = tid >> 6;
    const int wm = (w & 1) * 32, wn = (w >> 1) * 16;
    const int fr = lane & 15, q = lane >> 4;
    const int* mb = mask + (size_t)b * SS;
    const float* dbp = decb + (size_t)b * TT + bm;
    float* Crow = menerg + (size_t)b * TT * SS + (size_t)bm * SS;
    const int col = bn + wn + fr;
    const int mk = mb[col];
#pragma unroll
    for (int i = 0; i < 2; ++i) {
        float4 d4 = *(const float4*)(dbp + wm + 16 * i + 4 * q);
        float db[4] = {d4.x, d4.y, d4.z, d4.w};
#pragma unroll
        for (int r = 0; r < 4; ++r) {
            const int row = wm + 16 * i + 4 * q + r;
            Crow[(size_t)row * SS + col] = mk ? acc[i][r] + db[r] : NEG_INF_F;
        }
    }
}

// ---------------------------------------------------------------------------
// K3: softmax over S=512 -> attn fp32 + attn hi plane
// ---------------------------------------------------------------------------
__global__ __launch_bounds__(128) void k_softmax(const float* __restrict__ me,
                                                 float* __restrict__ attn,
                                                 u16* __restrict__ ahi) {
    const int row = blockIdx.x;
    const int tid = threadIdx.x;
    const float4 v = ((const float4*)(me + (size_t)row * SS))[tid];
    float m = fmaxf(fmaxf(v.x, v.y), fmaxf(v.z, v.w));
#pragma unroll
    for (int off = 32; off >= 1; off >>= 1) m = fmaxf(m, __shfl_xor(m, off, 64));
    __shared__ float redm[2];
    __shared__ float reds[2];
    const int wv = tid >> 6, lane = tid & 63;
    if (lane == 0) redm[wv] = m;
    __syncthreads();
    m = fmaxf(redm[0], redm[1]);
    float e0 = __expf(v.x - m), e1 = __expf(v.y - m);
    float e2 = __expf(v.z - m), e3 = __expf(v.w - m);
    float s = (e0 + e1) + (e2 + e3);
#pragma unroll
    for (int off = 32; off >= 1; off >>= 1) s += __shfl_xor(s, off, 64);
    if (lane == 0) reds[wv] = s;
    __syncthreads();
    s = reds[0] + reds[1];
    const float inv = 1.0f / s;
    float o0 = e0 * inv, o1 = e1 * inv, o2 = e2 * inv, o3 = e3 * inv;
    ((float4*)(attn + (size_t)row * SS))[tid] = make_float4(o0, o1, o2, o3);
    ((ushort4*)(ahi + (size_t)row * SS))[tid] =
        make_ushort4((u16)bf16_rne(o0), (u16)bf16_rne(o1),
                     (u16)bf16_rne(o2), (u16)bf16_rne(o3));
}

// ---------------------------------------------------------------------------
// K4: wc = attn @ enc -> wc hi plane. BM 64 -> grid (16, 2, 64) = 2048 ->
// 8 blk/CU (LDS 18 KB). Single-bf16, BK=64 subtiles.
// ---------------------------------------------------------------------------
__global__ __launch_bounds__(256) void k_ctx(const u16* __restrict__ Ahp,
                                             const float* __restrict__ enc,
                                             u16* __restrict__ Chi) {
    const int b = blockIdx.z;
    const int bn = blockIdx.x * BN;  // over E
    const int bm = blockIdx.y * BM2; // over T
    __shared__ u16 Ah[2][BM2 * ROWU];
    __shared__ unsigned Bp[2][BN * LDSTP];
    const int tid = threadIdx.x;
    const u16* Abh = Ahp + (size_t)b * TT * SS + (size_t)bm * SS;
    const float* Bm = enc + (size_t)b * SS * EE + bn;
    f32x4 acc[2][2] = {};
    for (int k0 = 0; k0 < SS; k0 += 2 * BK) {
        __syncthreads();
        stage_glds<BM2>(Ah[0], Abh + k0, SS, tid);
        stage_glds<BM2>(Ah[1], Abh + k0 + BK, SS, tid);
        stage_tr1(Bp[0], Bm + (size_t)k0 * EE, EE, tid);
        stage_tr1(Bp[1], Bm + (size_t)(k0 + BK) * EE, EE, tid);
        __builtin_amdgcn_s_waitcnt(0);
        __syncthreads();
        mfma_sbp1_64(Ah[0], Bp[0], acc, tid);
        mfma_sbp1_64(Ah[1], Bp[1], acc, tid);
    }
    const int lane = tid & 63, w = tid >> 6;
    const int wm = (w & 1) * 32, wn = (w >> 1) * 32;
    const int fr = lane & 15, q = lane >> 4;
    u16* Ch = Chi + (size_t)b * TT * EE + (size_t)bm * EE;
#pragma unroll
    for (int j = 0; j < 2; ++j) {
        const int col = bn + wn + 16 * j + fr;
#pragma unroll
        for (int i = 0; i < 2; ++i)
#pragma unroll
            for (int r = 0; r < 4; ++r) {
                const int row = wm + 16 * i + 4 * q + r;
                Ch[(size_t)row * EE + col] = (u16)bf16_rne(acc[i][j][r]);
            }
    }
}

// ---------------------------------------------------------------------------
// K5: h_tilde = tanh([wc | dec] @ W_out), all-single-bf16. BM 64 -> grid
// (128, 8) = 1024 -> 4 blk/CU (was 2). BK=64 subtiles.
// ---------------------------------------------------------------------------
__global__ __launch_bounds__(256) void k_out(const u16* __restrict__ wch,
                                             const u16* __restrict__ dech,
                                             const u16* __restrict__ woth,
                                             float* __restrict__ ht) {
    __shared__ u16 Ah[2][BM2 * ROWU], Bh[2][BN * ROWU];
    const int tid = threadIdx.x;
    const int bm = blockIdx.x * BM2, bn = blockIdx.y * BN;  // x = m for B-tile reuse
    const int KTOT = EE + DDIM;
    f32x4 acc[2][2] = {};
    for (int k0 = 0; k0 < KTOT; k0 += 2 * BK) {
        __syncthreads();
#pragma unroll
        for (int s = 0; s < 2; ++s) {
            const int kk = k0 + BK * s;
            const u16* ah;
            int ld;
            if (kk < EE) {
                ah = wch + (size_t)bm * EE + kk;
                ld = EE;
            } else {
                ah = dech + (size_t)bm * DDIM + (kk - EE);
                ld = DDIM;
            }
            stage_glds<BM2>(Ah[s], ah, ld, tid);
            stage_glds<BN>(Bh[s], woth + (size_t)bn * KTOT + kk, KTOT, tid);
        }
        __builtin_amdgcn_s_waitcnt(0);
        __syncthreads();
        mfma_ss1_64(Ah[0], Bh[0], acc, tid);
        mfma_ss1_64(Ah[1], Bh[1], acc, tid);
    }
    const int lane = tid & 63, w = tid >> 6;
    const int wm = (w & 1) * 32, wn = (w >> 1) * 32;
    const int fr = lane & 15, q = lane >> 4;
#pragma unroll
    for (int j = 0; j < 2; ++j) {
        const int col = bn + wn + 16 * j + fr;
#pragma unroll
        for (int i = 0; i < 2; ++i)
#pragma unroll
            for (int r = 0; r < 4; ++r) {
                const int row = bm + wm + 16 * i + 4 * q + r;
                ht[(size_t)row * DDIM + col] = fast_tanh(acc[i][j][r]);
            }
    }
}

// ---------------------------------------------------------------------------
extern "C" void kernel_launch(void* const* d_in, const int* in_sizes, int n_in,
                              void* d_out, int out_size, void* d_ws, size_t ws_size,
                              hipStream_t stream) {
    (void)in_sizes; (void)n_in; (void)out_size; (void)ws_size;
    const float* dec = (const float*)d_in[0];
    const float* enc = (const float*)d_in[1];
    const int* mask = (const int*)d_in[2];
    const float* Wa = (const float*)d_in[3];
    const float* ba = (const float*)d_in[4];
    const float* Wo = (const float*)d_in[5];

    float* h_tilde = (float*)d_out;
    float* attn = h_tilde + (size_t)BB * TT * DDIM;
    float* menerg = attn + (size_t)BB * TT * SS;

    // Workspace layout (bytes)
    char* ws = (char*)d_ws;
    u16* decW_hi = (u16*)(ws);                       // 8192x1024 u16 = 16.78 MB
    u16* dec_hi  = (u16*)(ws + 33554432);            // 8192x512
    u16* attn_hi = (u16*)(ws + 50331648);            // 8192x512
    u16* wa_hi   = (u16*)(ws + 67108864);            // 1024x512
    u16* wot_hi  = (u16*)(ws + 69206016);            // 512x1536
    float* decb  = (float*)(ws + 72351744);          // 8192 f32
    // wc plane aliases decW_hi (decW dead after k_energy)
    u16* wc_hi = decW_hi;

    k_prep<<<(BB * TT) / 4, 256, 0, stream>>>(dec, ba, dec_hi, decb);
    k_conv1<<<(EE * DDIM) / 4 / 256, 256, 0, stream>>>(Wa, wa_hi);
    k_wot<<<dim3((EE + DDIM) / 64, DDIM / 64), 256, 0, stream>>>(Wo, wot_hi);
    k_decw<<<dim3((BB * TT) / BM2, EE / BN), 256, 0, stream>>>(dec_hi, wa_hi, decW_hi);
    k_energy<<<dim3(SS / BNE, TT / BM2, BB), 256, 0, stream>>>(decW_hi, enc, mask, decb, menerg);
    k_softmax<<<BB * TT, 128, 0, stream>>>(menerg, attn, attn_hi);
    k_ctx<<<dim3(EE / BN, TT / BM2, BB), 256, 0, stream>>>(attn_hi, enc, wc_hi);
    k_out<<<dim3((BB * TT) / BM2, DDIM / BN), 256, 0, stream>>>(wc_hi, dec_hi, wot_hi, h_tilde);
}